// Round 5
// baseline (293.325 us; speedup 1.0000x reference)
//
#include <hip/hip_runtime.h>

// Involution: B=16, C=256, H=W=56, mid=64, GROUPS=16, GROUP_SIZE=16, K=3 (KK=9)
// All fp32. Output (16,256,56,56).
// Fully fused: conv1 (+BN+ReLU) -> LDS, conv2 -> regs, involution -> out.

#define Cn    256
#define MID   64
#define Hn    56
#define Wn    56
#define HW    3136
#define Bn    16
#define NPIX  (Bn * HW)       // 50176
#define CHW   (Cn * HW)
#define NKK   9
#define NG    16
#define GSZ   16
#define PXT   64              // pixels per block
#define LTP   68              // lt row pitch (measured 0 bank conflicts)
#define NBLK  (NPIX / PXT)    // 784
#define BPX   (NBLK / 8)      // 98 contiguous blocks per XCD slice
#define BN_EPS 1e-5f

// ---------------------------------------------------------------------------
// prep: w1f[c*64+o] = w1[o*256+c] * scale[o];  bias1[o] = beta[o]-mean[o]*scale[o]
// ---------------------------------------------------------------------------
__global__ __launch_bounds__(256) void prep_kernel(
    const float* __restrict__ w1,
    const float* __restrict__ gamma,
    const float* __restrict__ beta,
    const float* __restrict__ mean,
    const float* __restrict__ var,
    float* __restrict__ w1f,
    float* __restrict__ bias1) {
  int idx = blockIdx.x * 256 + threadIdx.x;
  if (idx < MID * Cn) {
    int c = idx >> 6;
    int o = idx & 63;
    float scale = gamma[o] / sqrtf(var[o] + BN_EPS);
    w1f[idx] = w1[o * Cn + c] * scale;
  } else if (idx < MID * Cn + MID) {
    int o = idx - MID * Cn;
    float scale = gamma[o] / sqrtf(var[o] + BN_EPS);
    bias1[o] = beta[o] - mean[o] * scale;
  }
}

// ---------------------------------------------------------------------------
// fused: block = 64 px, 512 threads (8 waves).
// Phase A: conv1 (64 mids x 64 px), x double-buffered via LDS, result -> lt.
// Phase B: conv2 -> 2 groups x 9 weights per thread, in registers.
// Phase C: involution, wave-uniform channel base + per-lane byte offsets.
// XCD-contiguous block swizzle so neighboring strips share one L2.
// ---------------------------------------------------------------------------
__global__ __launch_bounds__(512, 6) void fused_kernel(
    const float* __restrict__ x,
    const float* __restrict__ w1f,
    const float* __restrict__ bias1,
    const float* __restrict__ w2,
    const float* __restrict__ b2,
    float* __restrict__ out) {
  __shared__ float lx[2][16][PXT];     // 8 KB
  __shared__ float lt[PXT][LTP];       // 17.4 KB

  int tid = threadIdx.x;
  int px  = tid & 63;
  int wvu = __builtin_amdgcn_readfirstlane(tid >> 6);   // 0..7, wave-uniform

  int bid  = blockIdx.x;
  int bid2 = (bid & 7) * BPX + (bid >> 3);   // XCD slice gets contiguous px range
  int px0  = bid2 * PXT;
  int b    = px0 / HW;
  int hw0  = px0 - b * HW;

  const float* xb = x + (size_t)b * CHW + hw0 + px;

  // ---------------- phase A: conv1 -> lt ----------------
  float r0 = xb[(size_t)wvu * HW];
  float r1 = xb[(size_t)(wvu + 8) * HW];
  lx[0][wvu][px] = r0;
  lx[0][wvu + 8][px] = r1;
  __syncthreads();

  float acc[8];
#pragma unroll
  for (int j = 0; j < 8; ++j) acc[j] = 0.0f;

  for (int k = 0; k < 16; ++k) {       // 16 c-tiles of 16
    int cur = k & 1;
    if (k < 15) {
      r0 = xb[(size_t)((k + 1) * 16 + wvu) * HW];
      r1 = xb[(size_t)((k + 1) * 16 + wvu + 8) * HW];
    }
#pragma unroll
    for (int c = 0; c < 16; ++c) {
      float xv = lx[cur][c][px];
      const float* wr = w1f + ((k * 16 + c) << 6) + (wvu << 3);  // uniform
#pragma unroll
      for (int q = 0; q < 2; ++q) {
        float4 w4 = *(const float4*)(wr + q * 4);
        acc[q * 4 + 0] = fmaf(xv, w4.x, acc[q * 4 + 0]);
        acc[q * 4 + 1] = fmaf(xv, w4.y, acc[q * 4 + 1]);
        acc[q * 4 + 2] = fmaf(xv, w4.z, acc[q * 4 + 2]);
        acc[q * 4 + 3] = fmaf(xv, w4.w, acc[q * 4 + 3]);
      }
    }
    if (k < 15) {
      lx[1 - cur][wvu][px] = r0;
      lx[1 - cur][wvu + 8][px] = r1;
    }
    __syncthreads();
  }

#pragma unroll
  for (int j = 0; j < 8; ++j)
    lt[px][wvu * 8 + j] = fmaxf(acc[j] + bias1[wvu * 8 + j], 0.0f);
  __syncthreads();

  // ---------------- phase B: conv2 -> a[2][9] in registers ----------------
  float a[2][NKK];
#pragma unroll
  for (int gi = 0; gi < 2; ++gi)
#pragma unroll
    for (int kk = 0; kk < NKK; ++kk)
      a[gi][kk] = b2[(wvu * 2 + gi) * NKK + kk];

#pragma unroll
  for (int qt = 0; qt < 4; ++qt) {
    float tr[16];
#pragma unroll
    for (int q = 0; q < 4; ++q)
      *(float4*)&tr[q * 4] = *(const float4*)&lt[px][qt * 16 + q * 4];

#pragma unroll
    for (int gi = 0; gi < 2; ++gi) {
      int g = wvu * 2 + gi;
#pragma unroll
      for (int kk = 0; kk < NKK; ++kk) {
        const float4* wr = (const float4*)(w2 + (g * NKK + kk) * MID + qt * 16);
        float s = a[gi][kk];
#pragma unroll
        for (int q = 0; q < 4; ++q) {
          float4 w4 = wr[q];
          s = fmaf(tr[q * 4 + 0], w4.x, s);
          s = fmaf(tr[q * 4 + 1], w4.y, s);
          s = fmaf(tr[q * 4 + 2], w4.z, s);
          s = fmaf(tr[q * 4 + 3], w4.w, s);
        }
        a[gi][kk] = s;
      }
    }
  }

  // ---------------- phase C: involution ----------------
  int hw = hw0 + px;
  int h  = hw / Wn;
  int w  = hw - h * Wn;

  int boff[NKK];
  unsigned vmask = 0;
#pragma unroll
  for (int kk = 0; kk < NKK; ++kk) {
    int di = kk / 3 - 1;
    int dj = kk % 3 - 1;
    int h2 = h + di;
    int w2v = w + dj;
    bool valid = ((unsigned)h2 < (unsigned)Hn) && ((unsigned)w2v < (unsigned)Wn);
    boff[kk] = (valid ? (h2 * Wn + w2v) : hw) * 4;   // byte offset, in-bounds
    vmask |= (valid ? 1u : 0u) << kk;
  }

  const char* xpb = (const char*)(x + (size_t)b * CHW);
  float* ob = out + (size_t)b * CHW + hw;

#pragma unroll
  for (int gi = 0; gi < 2; ++gi) {
    int g = wvu * 2 + gi;
    float wk[NKK];
#pragma unroll
    for (int kk = 0; kk < NKK; ++kk)
      wk[kk] = ((vmask >> kk) & 1u) ? a[gi][kk] : 0.0f;

#pragma unroll
    for (int c2 = 0; c2 < 8; ++c2) {
      float xv[2][NKK];
#pragma unroll
      for (int cc = 0; cc < 2; ++cc) {
        const char* xc = xpb + (size_t)(g * GSZ + c2 * 2 + cc) * HW * 4;  // uniform base
#pragma unroll
        for (int kk = 0; kk < NKK; ++kk)
          xv[cc][kk] = *(const float*)(xc + boff[kk]);
      }
#pragma unroll
      for (int cc = 0; cc < 2; ++cc) {
        float s = 0.0f;
#pragma unroll
        for (int kk = 0; kk < NKK; ++kk)
          s = fmaf(wk[kk], xv[cc][kk], s);
        ob[(size_t)(g * GSZ + c2 * 2 + cc) * HW] = s;
      }
    }
  }
}

// ---------------------------------------------------------------------------
extern "C" void kernel_launch(void* const* d_in, const int* in_sizes, int n_in,
                              void* d_out, int out_size, void* d_ws, size_t ws_size,
                              hipStream_t stream) {
  const float* x     = (const float*)d_in[0];
  const float* w1    = (const float*)d_in[1];
  const float* gamma = (const float*)d_in[2];
  const float* beta  = (const float*)d_in[3];
  const float* mean  = (const float*)d_in[4];
  const float* var   = (const float*)d_in[5];
  const float* w2    = (const float*)d_in[6];
  const float* b2    = (const float*)d_in[7];
  float* out = (float*)d_out;

  // workspace: w1f (64 KB) | bias1 (256 B)  (t eliminated by fusion)
  char* ws = (char*)d_ws;
  float* w1f   = (float*)ws;
  float* bias1 = (float*)(ws + (size_t)MID * Cn * 4);

  prep_kernel<<<(MID * Cn + MID + 255) / 256, 256, 0, stream>>>(
      w1, gamma, beta, mean, var, w1f, bias1);
  fused_kernel<<<NBLK, 512, 0, stream>>>(x, w1f, bias1, w2, b2, out);
}

// Round 6
// 217.159 us; speedup vs baseline: 1.3507x; 1.3507x over previous
//
#include <hip/hip_runtime.h>

// Involution: B=16, C=256, H=W=56, mid=64, GROUPS=16, GROUP_SIZE=16, K=3 (KK=9)
// All fp32. Output (16,256,56,56).
// Fully fused: conv1 (+BN+ReLU) -> LDS, conv2 -> regs, involution -> out.
// NOTE: __launch_bounds__(512,4): at (512,6) the compiler capped at 40 VGPR and
// spilled to scratch -> WRITE_SIZE 260 MB (5x output), 207 us. Keep >=128 VGPR.

#define Cn    256
#define MID   64
#define Hn    56
#define Wn    56
#define HW    3136
#define Bn    16
#define NPIX  (Bn * HW)       // 50176
#define CHW   (Cn * HW)
#define NKK   9
#define NG    16
#define GSZ   16
#define PXT   64              // pixels per block
#define LTP   68              // lt row pitch (measured 0 bank conflicts)
#define NBLK  (NPIX / PXT)    // 784
#define BPX   (NBLK / 8)      // 98 contiguous blocks per XCD slice
#define BN_EPS 1e-5f

// ---------------------------------------------------------------------------
// prep: w1f[c*64+o] = w1[o*256+c] * scale[o];  bias1[o] = beta[o]-mean[o]*scale[o]
// ---------------------------------------------------------------------------
__global__ __launch_bounds__(256) void prep_kernel(
    const float* __restrict__ w1,
    const float* __restrict__ gamma,
    const float* __restrict__ beta,
    const float* __restrict__ mean,
    const float* __restrict__ var,
    float* __restrict__ w1f,
    float* __restrict__ bias1) {
  int idx = blockIdx.x * 256 + threadIdx.x;
  if (idx < MID * Cn) {
    int c = idx >> 6;
    int o = idx & 63;
    float scale = gamma[o] / sqrtf(var[o] + BN_EPS);
    w1f[idx] = w1[o * Cn + c] * scale;
  } else if (idx < MID * Cn + MID) {
    int o = idx - MID * Cn;
    float scale = gamma[o] / sqrtf(var[o] + BN_EPS);
    bias1[o] = beta[o] - mean[o] * scale;
  }
}

// ---------------------------------------------------------------------------
// fused: block = 64 px, 512 threads (8 waves).
// Phase A: conv1 (64 mids x 64 px), x double-buffered via LDS, result -> lt.
// Phase B: conv2 -> 2 groups x 9 weights per thread, in registers.
// Phase C: involution, wave-uniform channel base + per-lane byte offsets.
// XCD-contiguous block swizzle so neighboring strips share one L2.
// ---------------------------------------------------------------------------
__global__ __launch_bounds__(512, 4) void fused_kernel(
    const float* __restrict__ x,
    const float* __restrict__ w1f,
    const float* __restrict__ bias1,
    const float* __restrict__ w2,
    const float* __restrict__ b2,
    float* __restrict__ out) {
  __shared__ float lx[2][16][PXT];     // 8 KB
  __shared__ float lt[PXT][LTP];       // 17.4 KB

  int tid = threadIdx.x;
  int px  = tid & 63;
  int wvu = __builtin_amdgcn_readfirstlane(tid >> 6);   // 0..7, wave-uniform

  int bid  = blockIdx.x;
  int bid2 = (bid & 7) * BPX + (bid >> 3);   // XCD slice gets contiguous px range
  int px0  = bid2 * PXT;
  int b    = px0 / HW;
  int hw0  = px0 - b * HW;

  const float* xb = x + (size_t)b * CHW + hw0 + px;

  // ---------------- phase A: conv1 -> lt ----------------
  float r0 = xb[(size_t)wvu * HW];
  float r1 = xb[(size_t)(wvu + 8) * HW];
  lx[0][wvu][px] = r0;
  lx[0][wvu + 8][px] = r1;
  __syncthreads();

  float acc[8];
#pragma unroll
  for (int j = 0; j < 8; ++j) acc[j] = 0.0f;

  for (int k = 0; k < 16; ++k) {       // 16 c-tiles of 16
    int cur = k & 1;
    if (k < 15) {
      r0 = xb[(size_t)((k + 1) * 16 + wvu) * HW];
      r1 = xb[(size_t)((k + 1) * 16 + wvu + 8) * HW];
    }
#pragma unroll
    for (int c = 0; c < 16; ++c) {
      float xv = lx[cur][c][px];
      const float* wr = w1f + ((k * 16 + c) << 6) + (wvu << 3);  // uniform
#pragma unroll
      for (int q = 0; q < 2; ++q) {
        float4 w4 = *(const float4*)(wr + q * 4);
        acc[q * 4 + 0] = fmaf(xv, w4.x, acc[q * 4 + 0]);
        acc[q * 4 + 1] = fmaf(xv, w4.y, acc[q * 4 + 1]);
        acc[q * 4 + 2] = fmaf(xv, w4.z, acc[q * 4 + 2]);
        acc[q * 4 + 3] = fmaf(xv, w4.w, acc[q * 4 + 3]);
      }
    }
    if (k < 15) {
      lx[1 - cur][wvu][px] = r0;
      lx[1 - cur][wvu + 8][px] = r1;
    }
    __syncthreads();
  }

#pragma unroll
  for (int j = 0; j < 8; ++j)
    lt[px][wvu * 8 + j] = fmaxf(acc[j] + bias1[wvu * 8 + j], 0.0f);
  __syncthreads();

  // ---------------- phase B: conv2 -> a[2][9] in registers ----------------
  float a[2][NKK];
#pragma unroll
  for (int gi = 0; gi < 2; ++gi)
#pragma unroll
    for (int kk = 0; kk < NKK; ++kk)
      a[gi][kk] = b2[(wvu * 2 + gi) * NKK + kk];

#pragma unroll
  for (int qt = 0; qt < 4; ++qt) {
    float tr[16];
#pragma unroll
    for (int q = 0; q < 4; ++q)
      *(float4*)&tr[q * 4] = *(const float4*)&lt[px][qt * 16 + q * 4];

#pragma unroll
    for (int gi = 0; gi < 2; ++gi) {
      int g = wvu * 2 + gi;
#pragma unroll
      for (int kk = 0; kk < NKK; ++kk) {
        const float4* wr = (const float4*)(w2 + (g * NKK + kk) * MID + qt * 16);
        float s = a[gi][kk];
#pragma unroll
        for (int q = 0; q < 4; ++q) {
          float4 w4 = wr[q];
          s = fmaf(tr[q * 4 + 0], w4.x, s);
          s = fmaf(tr[q * 4 + 1], w4.y, s);
          s = fmaf(tr[q * 4 + 2], w4.z, s);
          s = fmaf(tr[q * 4 + 3], w4.w, s);
        }
        a[gi][kk] = s;
      }
    }
  }

  // ---------------- phase C: involution ----------------
  int hw = hw0 + px;
  int h  = hw / Wn;
  int w  = hw - h * Wn;

  int boff[NKK];
  unsigned vmask = 0;
#pragma unroll
  for (int kk = 0; kk < NKK; ++kk) {
    int di = kk / 3 - 1;
    int dj = kk % 3 - 1;
    int h2 = h + di;
    int w2v = w + dj;
    bool valid = ((unsigned)h2 < (unsigned)Hn) && ((unsigned)w2v < (unsigned)Wn);
    boff[kk] = (valid ? (h2 * Wn + w2v) : hw) * 4;   // byte offset, in-bounds
    vmask |= (valid ? 1u : 0u) << kk;
  }

  const char* xpb = (const char*)(x + (size_t)b * CHW);
  float* ob = out + (size_t)b * CHW + hw;

#pragma unroll
  for (int gi = 0; gi < 2; ++gi) {
    int g = wvu * 2 + gi;
    float wk[NKK];
#pragma unroll
    for (int kk = 0; kk < NKK; ++kk)
      wk[kk] = ((vmask >> kk) & 1u) ? a[gi][kk] : 0.0f;

#pragma unroll
    for (int c2 = 0; c2 < 8; ++c2) {
      float xv[2][NKK];
#pragma unroll
      for (int cc = 0; cc < 2; ++cc) {
        const char* xc = xpb + (size_t)(g * GSZ + c2 * 2 + cc) * HW * 4;  // uniform base
#pragma unroll
        for (int kk = 0; kk < NKK; ++kk)
          xv[cc][kk] = *(const float*)(xc + boff[kk]);
      }
#pragma unroll
      for (int cc = 0; cc < 2; ++cc) {
        float s = 0.0f;
#pragma unroll
        for (int kk = 0; kk < NKK; ++kk)
          s = fmaf(wk[kk], xv[cc][kk], s);
        ob[(size_t)(g * GSZ + c2 * 2 + cc) * HW] = s;
      }
    }
  }
}

// ---------------------------------------------------------------------------
extern "C" void kernel_launch(void* const* d_in, const int* in_sizes, int n_in,
                              void* d_out, int out_size, void* d_ws, size_t ws_size,
                              hipStream_t stream) {
  const float* x     = (const float*)d_in[0];
  const float* w1    = (const float*)d_in[1];
  const float* gamma = (const float*)d_in[2];
  const float* beta  = (const float*)d_in[3];
  const float* mean  = (const float*)d_in[4];
  const float* var   = (const float*)d_in[5];
  const float* w2    = (const float*)d_in[6];
  const float* b2    = (const float*)d_in[7];
  float* out = (float*)d_out;

  // workspace: w1f (64 KB) | bias1 (256 B)  (t eliminated by fusion)
  char* ws = (char*)d_ws;
  float* w1f   = (float*)ws;
  float* bias1 = (float*)(ws + (size_t)MID * Cn * 4);

  prep_kernel<<<(MID * Cn + MID + 255) / 256, 256, 0, stream>>>(
      w1, gamma, beta, mean, var, w1f, bias1);
  fused_kernel<<<NBLK, 512, 0, stream>>>(x, w1f, bias1, w2, b2, out);
}